// Round 6
// baseline (321.253 us; speedup 1.0000x reference)
//
#include <hip/hip_runtime.h>

// Reference collapses (softmax over size-1 axis == 1; reshapes are identity):
//   out = relu(x @ (gamma*W3 + W4)^T),  x:(B,20), fused M:(200,20)
// Memory floor: 210 MB out write + 21 MB x read => ~37 us @ 6.3 TB/s.
//
// R5 lesson: traffic is perfect (WRITE exactly 204,800 KB, FETCH 20 MB) but
// VGPR=48 proved the compiler's max-occupancy scheduler sank my unrolled
// loads next to their uses -> still one exposed load-chain per iteration.
// R6: __launch_bounds__(256,4) raises the scheduler's register budget to
// 128, and an explicit prefetch-1 double buffer in a fully-unrolled loop
// keeps the next x-row load in flight behind every FMA block. Grid 6400
// (25 short blocks/CU) removes the 3200-block drain imbalance.

#define BATCH    262144
#define DICT     20
#define COLS     200                         // NUM_HEADS * DICT
#define NTHREADS 256
#define NBLOCKS  6400
#define TOTALT   (NBLOCKS * NTHREADS)        // 1,638,400 threads
#define ROWSWEEP (TOTALT / 100)              // 16,384 rows per sweep (stride%100==0)
#define ITERS    (BATCH / ROWSWEEP)          // 16, exact — no tail

__global__ __launch_bounds__(NTHREADS, 4)    // 128-VGPR budget, 4 waves/EU
void attn_collapsed_kernel(const float* __restrict__ x,
                           const float* __restrict__ W3,
                           const float* __restrict__ W4,
                           const float* __restrict__ gamma,
                           float* __restrict__ out)
{
    const int tid = blockIdx.x * NTHREADS + threadIdx.x;
    const int j2  = tid % 100;               // fixed column pair: 2*j2, 2*j2+1
    const int r0  = tid / 100;               // rows r0 + i*ROWSWEEP
    const float g = gamma[0];

    // Fused weights for the 2 owned columns -> 40 VGPRs.
    float4 m0[5], m1[5];
    {
        const float4* w3a = (const float4*)(W3 + (2 * j2 + 0) * DICT);
        const float4* w4a = (const float4*)(W4 + (2 * j2 + 0) * DICT);
        const float4* w3b = (const float4*)(W3 + (2 * j2 + 1) * DICT);
        const float4* w4b = (const float4*)(W4 + (2 * j2 + 1) * DICT);
#pragma unroll
        for (int i = 0; i < 5; ++i) {
            float4 a = w3a[i], b = w4a[i];
            m0[i].x = fmaf(g, a.x, b.x);
            m0[i].y = fmaf(g, a.y, b.y);
            m0[i].z = fmaf(g, a.z, b.z);
            m0[i].w = fmaf(g, a.w, b.w);
            a = w3b[i]; b = w4b[i];
            m1[i].x = fmaf(g, a.x, b.x);
            m1[i].y = fmaf(g, a.y, b.y);
            m1[i].z = fmaf(g, a.z, b.z);
            m1[i].w = fmaf(g, a.w, b.w);
        }
    }

    float2* out2 = (float2*)out;
    const int obase = r0 * 100 + j2;         // + i*TOTALT per iter

    // Prefetch-distance-1 double buffer; guards fold under full unroll.
    float4 xv[2][5];
    {
        const float4* xr = (const float4*)(x + r0 * DICT);
#pragma unroll
        for (int k = 0; k < 5; ++k) xv[0][k] = xr[k];
    }

#pragma unroll
    for (int i = 0; i < ITERS; ++i) {
        const int cur = i & 1, nxt = cur ^ 1;
        if (i + 1 < ITERS) {                 // compile-time-folded guard
            const float4* xr = (const float4*)(x + (r0 + (i + 1) * ROWSWEEP) * DICT);
#pragma unroll
            for (int k = 0; k < 5; ++k) xv[nxt][k] = xr[k];
        }

        float ax = 0.f, ay = 0.f;
#pragma unroll
        for (int k = 0; k < 5; ++k) {
            const float4 xx = xv[cur][k];
            ax = fmaf(xx.x, m0[k].x, ax);
            ax = fmaf(xx.y, m0[k].y, ax);
            ax = fmaf(xx.z, m0[k].z, ax);
            ax = fmaf(xx.w, m0[k].w, ax);
            ay = fmaf(xx.x, m1[k].x, ay);
            ay = fmaf(xx.y, m1[k].y, ay);
            ay = fmaf(xx.z, m1[k].z, ay);
            ay = fmaf(xx.w, m1[k].w, ay);
        }
        float2 res;
        res.x = fmaxf(ax, 0.f);
        res.y = fmaxf(ay, 0.f);
        out2[obase + i * TOTALT] = res;      // lane-consecutive 512 B/wave
    }
}

extern "C" void kernel_launch(void* const* d_in, const int* in_sizes, int n_in,
                              void* d_out, int out_size, void* d_ws, size_t ws_size,
                              hipStream_t stream) {
    const float* x     = (const float*)d_in[0];
    // d_in[1] = W1, d_in[2] = W2 : mathematically unused (softmax over size-1 axis)
    const float* W3    = (const float*)d_in[3];
    const float* W4    = (const float*)d_in[4];
    const float* gamma = (const float*)d_in[5];
    float* out = (float*)d_out;

    attn_collapsed_kernel<<<NBLOCKS, NTHREADS, 0, stream>>>(x, W3, W4, gamma, out);
}